// Round 3
// baseline (570.776 us; speedup 1.0000x reference)
//
#include <hip/hip_runtime.h>

// SkipConnection MLP: x[B,2] -> Linear(2,4)+ReLU -> 99x [Linear(4,4)+ReLU
// (+skip when i%5!=0)] -> Linear(4,1).
// fp32 VALU compute-bound (~26.6 GFLOP). One row per lane, activations in
// VGPRs, weights read via wave-uniform loads (expect s_load -> SGPR operands).

#define NLAYERS 99

__global__ __launch_bounds__(256) void skipmlp_kernel(
    const float* __restrict__ x,      // [B,2]
    const float* __restrict__ W_in,   // [2,4]
    const float* __restrict__ b_in,   // [4]
    const float* __restrict__ Ws,     // [99,4,4]
    const float* __restrict__ bs,     // [99,4]
    const float* __restrict__ W_out,  // [4,1]
    const float* __restrict__ b_out,  // [1]
    float* __restrict__ out,          // [B,1]
    int B)
{
    int row = blockIdx.x * blockDim.x + threadIdx.x;
    if (row >= B) return;

    const float2 xv = *reinterpret_cast<const float2*>(x + (size_t)row * 2u);

    // input layer: h[c] = relu(x0*W_in[0][c] + x1*W_in[1][c] + b_in[c])
    float o0 = fmaxf(fmaf(xv.x, W_in[0], fmaf(xv.y, W_in[4], b_in[0])), 0.f);
    float o1 = fmaxf(fmaf(xv.x, W_in[1], fmaf(xv.y, W_in[5], b_in[1])), 0.f);
    float o2 = fmaxf(fmaf(xv.x, W_in[2], fmaf(xv.y, W_in[6], b_in[2])), 0.f);
    float o3 = fmaxf(fmaf(xv.x, W_in[3], fmaf(xv.y, W_in[7], b_in[3])), 0.f);

    float s0 = o0, s1 = o1, s2 = o2, s3 = o3;

    // 99 hidden layers; flag = (i % 5 != 0): residual add + skip update.
    // unroll by 5 so the flag folds to a compile-time constant per copy.
    #pragma unroll 5
    for (int i = 0; i < NLAYERS; ++i) {
        const float* __restrict__ W = Ws + i * 16;  // [4][4], row-major (j,c)
        const float* __restrict__ b = bs + i * 4;

        float h0 = fmaf(o0, W[ 0], fmaf(o1, W[ 4], fmaf(o2, W[ 8], fmaf(o3, W[12], b[0]))));
        float h1 = fmaf(o0, W[ 1], fmaf(o1, W[ 5], fmaf(o2, W[ 9], fmaf(o3, W[13], b[1]))));
        float h2 = fmaf(o0, W[ 2], fmaf(o1, W[ 6], fmaf(o2, W[10], fmaf(o3, W[14], b[2]))));
        float h3 = fmaf(o0, W[ 3], fmaf(o1, W[ 7], fmaf(o2, W[11], fmaf(o3, W[15], b[3]))));
        h0 = fmaxf(h0, 0.f);
        h1 = fmaxf(h1, 0.f);
        h2 = fmaxf(h2, 0.f);
        h3 = fmaxf(h3, 0.f);

        if ((i % 5) != 0) {
            o0 = h0 + s0; o1 = h1 + s1; o2 = h2 + s2; o3 = h3 + s3;
            s0 = o0; s1 = o1; s2 = o2; s3 = o3;
        } else {
            o0 = h0; o1 = h1; o2 = h2; o3 = h3;
        }
    }

    float y = fmaf(o0, W_out[0], fmaf(o1, W_out[1], fmaf(o2, W_out[2], fmaf(o3, W_out[3], b_out[0]))));
    out[row] = y;
}

extern "C" void kernel_launch(void* const* d_in, const int* in_sizes, int n_in,
                              void* d_out, int out_size, void* d_ws, size_t ws_size,
                              hipStream_t stream) {
    const float* x     = (const float*)d_in[0];
    const float* W_in  = (const float*)d_in[1];
    const float* b_in  = (const float*)d_in[2];
    const float* Ws    = (const float*)d_in[3];
    const float* bs    = (const float*)d_in[4];
    const float* W_out = (const float*)d_in[5];
    const float* b_out = (const float*)d_in[6];
    float* out = (float*)d_out;

    const int B = in_sizes[0] / 2;  // x is [B,2]
    const int block = 256;
    const int grid = (B + block - 1) / block;

    skipmlp_kernel<<<grid, block, 0, stream>>>(x, W_in, b_in, Ws, bs, W_out, b_out, out, B);
}

// Round 4
// 569.744 us; speedup vs baseline: 1.0018x; 1.0018x over previous
//
#include <hip/hip_runtime.h>

// SkipConnection MLP, packed-fp32 experiment.
// 2 rows per lane packed into (lo,hi) of VGPR pairs; v_pk_fma_f32 /
// v_pk_add_f32 via inline asm with SGPR-pair weight operands (weights &
// biases pre-duplicated to (w,w) float2 in d_ws by prep kernel).
// ReLU stays scalar (no v_pk_max_f32 on CDNA).

#define NLAYERS 99

__global__ void prep_dup_kernel(const float* __restrict__ Ws,
                                const float* __restrict__ bs,
                                float2* __restrict__ ws) {
    int i = blockIdx.x * blockDim.x + threadIdx.x;
    if (i < NLAYERS * 16) ws[i] = make_float2(Ws[i], Ws[i]);
    if (i < NLAYERS * 4)  ws[NLAYERS * 16 + i] = make_float2(bs[i], bs[i]);
}

#define PK_FMA(h, o, w) \
    asm("v_pk_fma_f32 %0, %1, %2, %0" : "+v"(h) : "v"(o), "s"(w))
#define PK_ADD(d, a, b_) \
    asm("v_pk_add_f32 %0, %1, %2" : "=v"(d) : "v"(a), "v"(b_))

__global__ __launch_bounds__(256) void skipmlp_pk_kernel(
    const float* __restrict__ x,      // [B,2]
    const float* __restrict__ W_in,   // [2,4]
    const float* __restrict__ b_in,   // [4]
    const float2* __restrict__ W2,    // [99*16] duplicated weights (in ws)
    const float* __restrict__ W_out,  // [4,1]
    const float* __restrict__ b_out,  // [1]
    float* __restrict__ out,          // [B,1]
    int B2)                           // B/2
{
    int t = blockIdx.x * blockDim.x + threadIdx.x;
    if (t >= B2) return;

    const float2* __restrict__ b2 = W2 + NLAYERS * 16;

    // rows 2t (A) and 2t+1 (B): x4 = (xA0, xA1, xB0, xB1) — coalesced 16B.
    const float4 xv = *reinterpret_cast<const float4*>(x + (size_t)t * 4u);

    // input layer, scalar (1/99 of the work)
    float oA0 = fmaxf(fmaf(xv.x, W_in[0], fmaf(xv.y, W_in[4], b_in[0])), 0.f);
    float oA1 = fmaxf(fmaf(xv.x, W_in[1], fmaf(xv.y, W_in[5], b_in[1])), 0.f);
    float oA2 = fmaxf(fmaf(xv.x, W_in[2], fmaf(xv.y, W_in[6], b_in[2])), 0.f);
    float oA3 = fmaxf(fmaf(xv.x, W_in[3], fmaf(xv.y, W_in[7], b_in[3])), 0.f);
    float oB0 = fmaxf(fmaf(xv.z, W_in[0], fmaf(xv.w, W_in[4], b_in[0])), 0.f);
    float oB1 = fmaxf(fmaf(xv.z, W_in[1], fmaf(xv.w, W_in[5], b_in[1])), 0.f);
    float oB2 = fmaxf(fmaf(xv.z, W_in[2], fmaf(xv.w, W_in[6], b_in[2])), 0.f);
    float oB3 = fmaxf(fmaf(xv.z, W_in[3], fmaf(xv.w, W_in[7], b_in[3])), 0.f);

    float2 o0 = make_float2(oA0, oB0);
    float2 o1 = make_float2(oA1, oB1);
    float2 o2 = make_float2(oA2, oB2);
    float2 o3 = make_float2(oA3, oB3);
    float2 s0 = o0, s1 = o1, s2 = o2, s3 = o3;

    #pragma unroll 5
    for (int i = 0; i < NLAYERS; ++i) {
        const float2* __restrict__ W = W2 + i * 16;  // W[j*4+c] = Ws[i][j][c] duplicated

        float2 h0 = b2[i * 4 + 0];
        float2 h1 = b2[i * 4 + 1];
        float2 h2 = b2[i * 4 + 2];
        float2 h3 = b2[i * 4 + 3];

        PK_FMA(h0, o0, W[ 0]); PK_FMA(h1, o0, W[ 1]); PK_FMA(h2, o0, W[ 2]); PK_FMA(h3, o0, W[ 3]);
        PK_FMA(h0, o1, W[ 4]); PK_FMA(h1, o1, W[ 5]); PK_FMA(h2, o1, W[ 6]); PK_FMA(h3, o1, W[ 7]);
        PK_FMA(h0, o2, W[ 8]); PK_FMA(h1, o2, W[ 9]); PK_FMA(h2, o2, W[10]); PK_FMA(h3, o2, W[11]);
        PK_FMA(h0, o3, W[12]); PK_FMA(h1, o3, W[13]); PK_FMA(h2, o3, W[14]); PK_FMA(h3, o3, W[15]);

        // ReLU (scalar halves; no v_pk_max_f32)
        h0.x = fmaxf(h0.x, 0.f); h0.y = fmaxf(h0.y, 0.f);
        h1.x = fmaxf(h1.x, 0.f); h1.y = fmaxf(h1.y, 0.f);
        h2.x = fmaxf(h2.x, 0.f); h2.y = fmaxf(h2.y, 0.f);
        h3.x = fmaxf(h3.x, 0.f); h3.y = fmaxf(h3.y, 0.f);

        if ((i % 5) != 0) {
            PK_ADD(o0, h0, s0); PK_ADD(o1, h1, s1); PK_ADD(o2, h2, s2); PK_ADD(o3, h3, s3);
            s0 = o0; s1 = o1; s2 = o2; s3 = o3;
        } else {
            o0 = h0; o1 = h1; o2 = h2; o3 = h3;
        }
    }

    // output layer, scalar
    float yA = fmaf(o0.x, W_out[0], fmaf(o1.x, W_out[1], fmaf(o2.x, W_out[2], fmaf(o3.x, W_out[3], b_out[0]))));
    float yB = fmaf(o0.y, W_out[0], fmaf(o1.y, W_out[1], fmaf(o2.y, W_out[2], fmaf(o3.y, W_out[3], b_out[0]))));
    *reinterpret_cast<float2*>(out + (size_t)t * 2u) = make_float2(yA, yB);
}

extern "C" void kernel_launch(void* const* d_in, const int* in_sizes, int n_in,
                              void* d_out, int out_size, void* d_ws, size_t ws_size,
                              hipStream_t stream) {
    const float* x     = (const float*)d_in[0];
    const float* W_in  = (const float*)d_in[1];
    const float* b_in  = (const float*)d_in[2];
    const float* Ws    = (const float*)d_in[3];
    const float* bs    = (const float*)d_in[4];
    const float* W_out = (const float*)d_in[5];
    const float* b_out = (const float*)d_in[6];
    float* out = (float*)d_out;
    float2* ws = (float2*)d_ws;   // [99*16 + 99*4] duplicated (w,w) pairs

    const int B = in_sizes[0] / 2;   // x is [B,2]
    const int B2 = B / 2;            // 2 rows per lane

    // duplicate weights+biases into ws (runs every call; ws re-poisoned each call)
    prep_dup_kernel<<<(NLAYERS * 16 + 255) / 256, 256, 0, stream>>>(Ws, bs, ws);

    const int block = 256;
    const int grid = (B2 + block - 1) / block;
    skipmlp_pk_kernel<<<grid, block, 0, stream>>>(x, W_in, b_in, ws, W_out, b_out, out, B2);
}

// Round 5
// 536.530 us; speedup vs baseline: 1.0638x; 1.0619x over previous
//
#include <hip/hip_runtime.h>

// SkipConnection MLP, fp32 VALU (only numerically-viable pipe; see journal:
// fp32 reassoc error is already 0.23% of the 2% budget -> amplification
// ~2e4*eps kills bf16/fp16/MFMA).
//
// Levers this round:
//  - relu+residual+bias fusion: s >= 0 always, so relu(pre)+s = max(pre+s, s),
//    with (b+s) as the fma-chain init: 6 ops/component, 24/layer (was 27.2).
//  - full unroll: let the scalar unit pipeline s_loads across layers
//    (unroll-5 showed SGPR=64 -> per-layer s_load serialization).

#define NLAYERS 99

__global__ __launch_bounds__(256) void skipmlp_kernel(
    const float* __restrict__ x,      // [B,2]
    const float* __restrict__ W_in,   // [2,4]
    const float* __restrict__ b_in,   // [4]
    const float* __restrict__ Ws,     // [99,4,4]
    const float* __restrict__ bs,     // [99,4]
    const float* __restrict__ W_out,  // [4,1]
    const float* __restrict__ b_out,  // [1]
    float* __restrict__ out,          // [B,1]
    int B)
{
    int row = blockIdx.x * blockDim.x + threadIdx.x;
    if (row >= B) return;

    const float2 xv = *reinterpret_cast<const float2*>(x + (size_t)row * 2u);

    // input layer: o = relu(x @ W_in + b_in)
    float o0 = fmaxf(fmaf(xv.x, W_in[0], fmaf(xv.y, W_in[4], b_in[0])), 0.f);
    float o1 = fmaxf(fmaf(xv.x, W_in[1], fmaf(xv.y, W_in[5], b_in[1])), 0.f);
    float o2 = fmaxf(fmaf(xv.x, W_in[2], fmaf(xv.y, W_in[6], b_in[2])), 0.f);
    float o3 = fmaxf(fmaf(xv.x, W_in[3], fmaf(xv.y, W_in[7], b_in[3])), 0.f);

    float s0 = o0, s1 = o1, s2 = o2, s3 = o3;

    #pragma unroll
    for (int i = 0; i < NLAYERS; ++i) {
        const float* __restrict__ W = Ws + i * 16;  // [j][c] row-major
        const float* __restrict__ b = bs + i * 4;

        if ((i % 5) != 0) {
            // residual layer: o_new = relu(pre) + s = max(pre + s, s)  (s >= 0)
            // (b+s) rides as the fma-chain init: no bias mov, no separate add.
            float p0 = fmaf(o0, W[ 0], fmaf(o1, W[ 4], fmaf(o2, W[ 8], fmaf(o3, W[12], b[0] + s0))));
            float p1 = fmaf(o0, W[ 1], fmaf(o1, W[ 5], fmaf(o2, W[ 9], fmaf(o3, W[13], b[1] + s1))));
            float p2 = fmaf(o0, W[ 2], fmaf(o1, W[ 6], fmaf(o2, W[10], fmaf(o3, W[14], b[2] + s2))));
            float p3 = fmaf(o0, W[ 3], fmaf(o1, W[ 7], fmaf(o2, W[11], fmaf(o3, W[15], b[3] + s3))));
            o0 = fmaxf(p0, s0);
            o1 = fmaxf(p1, s1);
            o2 = fmaxf(p2, s2);
            o3 = fmaxf(p3, s3);
            s0 = o0; s1 = o1; s2 = o2; s3 = o3;
        } else {
            // plain layer: o_new = relu(pre); skip unchanged.
            // mul + 3 fma + add(b, SGPR-legal) + max(.,0)
            float p0 = fmaf(o0, W[ 0], fmaf(o1, W[ 4], fmaf(o2, W[ 8], o3 * W[12]))) + b[0];
            float p1 = fmaf(o0, W[ 1], fmaf(o1, W[ 5], fmaf(o2, W[ 9], o3 * W[13]))) + b[1];
            float p2 = fmaf(o0, W[ 2], fmaf(o1, W[ 6], fmaf(o2, W[10], o3 * W[14]))) + b[2];
            float p3 = fmaf(o0, W[ 3], fmaf(o1, W[ 7], fmaf(o2, W[11], o3 * W[15]))) + b[3];
            o0 = fmaxf(p0, 0.f);
            o1 = fmaxf(p1, 0.f);
            o2 = fmaxf(p2, 0.f);
            o3 = fmaxf(p3, 0.f);
        }
    }

    float y = fmaf(o0, W_out[0], fmaf(o1, W_out[1], fmaf(o2, W_out[2], o3 * W_out[3]))) + b_out[0];
    out[row] = y;
}

extern "C" void kernel_launch(void* const* d_in, const int* in_sizes, int n_in,
                              void* d_out, int out_size, void* d_ws, size_t ws_size,
                              hipStream_t stream) {
    const float* x     = (const float*)d_in[0];
    const float* W_in  = (const float*)d_in[1];
    const float* b_in  = (const float*)d_in[2];
    const float* Ws    = (const float*)d_in[3];
    const float* bs    = (const float*)d_in[4];
    const float* W_out = (const float*)d_in[5];
    const float* b_out = (const float*)d_in[6];
    float* out = (float*)d_out;

    const int B = in_sizes[0] / 2;  // x is [B,2]
    const int block = 256;
    const int grid = (B + block - 1) / block;

    skipmlp_kernel<<<grid, block, 0, stream>>>(x, W_in, b_in, Ws, bs, W_out, b_out, out, B);
}